// Round 7
// baseline (266.984 us; speedup 1.0000x reference)
//
#include <hip/hip_runtime.h>
#include <math.h>

#define NB 32
#define CB 64
#define HH 224
#define WW 224
#define PADP 2
#define HP (HH + 2*PADP)   // 228
#define WP (WW + 2*PADP)   // 228
#define HW (HH*WW)         // 50176
#define HWP (HP*WP)        // 51984
#define EPSV 1e-5f
#define CHUNKS 49          // HW / 1024
#define GROUPS 57          // HP / 4

typedef float v4f __attribute__((ext_vector_type(4)));

// fast sigmoid: v_exp + v_rcp (error ~1e-6, budget is 3e-2)
__device__ __forceinline__ float fsig(float v) {
    float e = __expf(-v);
    return __builtin_amdgcn_rcpf(1.0f + e);
}
// tanh-form GELU == v*sigmoid(1.59577v + 0.071355v^3); max dev ~1e-3 << 3.3e-2 budget
__device__ __forceinline__ float fgelu(float v) {
    float t = v * (1.5957691216f + 0.0713548162f * v * v);
    return v * fsig(t);
}
__device__ __forceinline__ float edgew(int w) {
    return 1.0f + (float)((w == 1) | (w == 2) | (w == WW-3) | (w == WW-2));
}

// ---------------- Pass 1: block = (n, 1024-float chunk); wave v owns the
// 256-float quarter (1 float4/lane) and loops ALL 64 channels with register
// gate carry (reads 65/64 of x instead of 17/16). Per-channel 64-lane shfl
// reduce; 4 waves' partials folded via 2KB LDS -> same partG/partX layout.
__global__ __launch_bounds__(256) void k_pool4(const float* __restrict__ x,
                                               float* __restrict__ partG,
                                               float* __restrict__ partX) {
    int b = blockIdx.x;
    int n = b / CHUNKS;
    int chunk = b - n * CHUNKS;
    int wave = threadIdx.x >> 6;
    int lane = threadIdx.x & 63;

    int p0 = chunk * 1024 + wave * 256 + lane * 4;   // float4-aligned; WW%4==0
    int h  = p0 / WW;
    int w0 = p0 - h * WW;
    float wh = 1.0f + (float)((h == 1) | (h == 2) | (h == HH-3) | (h == HH-2));
    float wg0 = wh * edgew(w0);
    float wg1 = wh * edgew(w0 + 1);
    float wg2 = wh * edgew(w0 + 2);
    float wg3 = wh * edgew(w0 + 3);

    const float* xn = x + (size_t)n * CB * HW;
    v4f prev = __builtin_nontemporal_load((const v4f*)(xn + (size_t)(CB-1) * HW + p0));

    __shared__ float lG[4][CB];
    __shared__ float lX[4][CB];

    for (int c = 0; c < CB; ++c) {
        v4f cur = __builtin_nontemporal_load((const v4f*)(xn + (size_t)c * HW + p0));
        float sG = wg0 * cur.x * fsig(prev.x)
                 + wg1 * cur.y * fsig(prev.y)
                 + wg2 * cur.z * fsig(prev.z)
                 + wg3 * cur.w * fsig(prev.w);
        float sX = wg0 * cur.x + wg1 * cur.y + wg2 * cur.z + wg3 * cur.w;
        #pragma unroll
        for (int off = 32; off >= 1; off >>= 1) {
            sG += __shfl_xor(sG, off);
            sX += __shfl_xor(sX, off);
        }
        if (lane == 0) { lG[wave][c] = sG; lX[wave][c] = sX; }
        prev = cur;
    }
    __syncthreads();
    if (threadIdx.x < 128) {
        int c = threadIdx.x & 63, which = threadIdx.x >> 6;
        size_t idx = ((size_t)n * CB + c) * CHUNKS + chunk;
        if (which == 0) partG[idx] = lG[0][c] + lG[1][c] + lG[2][c] + lG[3][c];
        else            partX[idx] = lX[0][c] + lX[1][c] + lX[2][c] + lX[3][c];
    }
}

// ---------------- Merged stats: fold 49 chunk-partials per (n,c), then BN
// (batch mean/biased var across n) + sigmoid -> scale; also writes cmean.
__global__ __launch_bounds__(256) void k_stats(const float* __restrict__ partG,
                                               const float* __restrict__ partX,
                                               const float* __restrict__ bnw,
                                               const float* __restrict__ bnb,
                                               float* __restrict__ cmean,
                                               float* __restrict__ scale) {
    int c = blockIdx.x;
    int t = threadIdx.x;
    int n = t >> 3, j0 = t & 7;
    float g = 0.f, xx = 0.f;
    for (int j = j0; j < CHUNKS; j += 8) {
        size_t idx = ((size_t)n * CB + c) * CHUNKS + j;
        g  += partG[idx];
        xx += partX[idx];
    }
    #pragma unroll
    for (int off = 4; off >= 1; off >>= 1) {
        g  += __shfl_xor(g, off);
        xx += __shfl_xor(xx, off);
    }
    __shared__ float lG[NB];
    if (j0 == 0) {
        lG[n] = g;
        cmean[n * CB + c] = xx * (1.0f / (float)HWP);
    }
    __syncthreads();
    if (t < NB) {
        float p = lG[t] * (1.0f / (float)HWP);     // pooled[t][c]
        float s = p;
        #pragma unroll
        for (int off = 16; off >= 1; off >>= 1) s += __shfl_xor(s, off);
        float mu = s * (1.0f / 32.0f);
        float d = p - mu;
        float q = d * d;
        #pragma unroll
        for (int off = 16; off >= 1; off >>= 1) q += __shfl_xor(q, off);
        float var = q * (1.0f / 32.0f);
        float normed = d * rsqrtf(var + EPSV) * bnw[c] + bnb[c];
        scale[t * CB + c] = 1.0f / (1.0f + expf(-normed));
    }
}

// ---------------- Output pass: block = (n, group of 4 consecutive padded rows)
// -> per-channel write set is exactly 57 whole 64B lines (no partial-line RMW).
// Wave v owns row hp=4g+v and loops ALL 64 channels (gate re-read 65/64).
// XCD swizzle: 1824 blocks = 8 XCDs x 228 contiguous groups (4 images each).
__global__ __launch_bounds__(256) void k_out2(const float* __restrict__ x,
                                              const float* __restrict__ scale,
                                              const float* __restrict__ cmean,
                                              const float* __restrict__ post_scale,
                                              float* __restrict__ out) {
    int o = blockIdx.x;
    int b = (o & 7) * (NB * GROUPS / 8) + (o >> 3);
    int n = b / GROUPS;
    int g = b - n * GROUPS;
    int wave = threadIdx.x >> 6;
    int lane = threadIdx.x & 63;
    int hp = g * 4 + wave;
    int rh = hp - PADP; rh = rh < 0 ? -rh : (rh >= HH ? 2*HH - 2 - rh : rh);
    bool act = lane < 56;
    float ps = post_scale[0];

    const float* xrow = x + (size_t)n * CB * HW + (size_t)rh * WW;
    const float* sc_row = scale + n * CB;
    const float* cm_row = cmean + n * CB;

    v4f prev = {0.f, 0.f, 0.f, 0.f};
    if (act) prev = __builtin_nontemporal_load((const v4f*)(xrow + (size_t)(CB-1) * HW + 4 * lane));

    for (int c = 0; c < CB; ++c) {
        v4f cur = {0.f, 0.f, 0.f, 0.f};
        if (act) cur = __builtin_nontemporal_load((const v4f*)(xrow + (size_t)c * HW + 4 * lane));
        float scp = sc_row[c] * ps;         // uniform -> s_load
        float cmp = cm_row[c] * ps;
        float o0 = fgelu(fmaf(cur.x * fsig(prev.x), scp, cmp));
        float o1 = fgelu(fmaf(cur.y * fsig(prev.y), scp, cmp));
        float o2 = fgelu(fmaf(cur.z * fsig(prev.z), scp, cmp));
        float o3 = fgelu(fmaf(cur.w * fsig(prev.w), scp, cmp));
        // shift left-neighbor's values in: lane l store covers wp=4l..4l+3
        float o1s = __shfl(o1, lane - 1);
        float o2s = __shfl(o2, lane - 1);
        float o3s = __shfl(o3, lane - 1);
        v4f st = { o2s, o3s, o0, o1 };          // interior: rw 4l-2..4l+1
        if (lane == 0)  st = (v4f){ o2, o1, o0, o1 };        // wp0<-rw2, wp1<-rw1, wp2<-rw0, wp3<-rw1
        if (lane == 56) st = (v4f){ o2s, o3s, o2s, o1s };    // wp224..227 <- rw222,223,222,221
        if (lane < 57) {
            float* orow = out + ((size_t)n * CB + c) * HWP + (size_t)hp * WP;
            __builtin_nontemporal_store(st, (v4f*)(orow + 4 * lane));
        }
        prev = cur;
    }
}

extern "C" void kernel_launch(void* const* d_in, const int* in_sizes, int n_in,
                              void* d_out, int out_size, void* d_ws, size_t ws_size,
                              hipStream_t stream) {
    const float* x   = (const float*)d_in[0];
    const float* bnw = (const float*)d_in[1];
    const float* bnb = (const float*)d_in[2];
    const float* ps  = (const float*)d_in[3];
    float* out = (float*)d_out;

    size_t npart = (size_t)NB * CB * CHUNKS;
    float* partG  = (float*)d_ws;
    float* partX  = partG + npart;
    float* cmean  = partX + npart;
    float* scale  = cmean + NB * CB;

    k_pool4<<<NB * CHUNKS, 256, 0, stream>>>(x, partG, partX);
    k_stats<<<CB, 256, 0, stream>>>(partG, partX, bnw, bnb, cmean, scale);
    k_out2<<<NB * GROUPS, 256, 0, stream>>>(x, scale, cmean, ps, out);
}

// Round 8
// 252.844 us; speedup vs baseline: 1.0559x; 1.0559x over previous
//
#include <hip/hip_runtime.h>
#include <math.h>

#define NB 32
#define CB 64
#define HH 224
#define WW 224
#define PADP 2
#define HP (HH + 2*PADP)   // 228
#define WP (WW + 2*PADP)   // 228
#define HW (HH*WW)         // 50176
#define HWP (HP*WP)        // 51984
#define EPSV 1e-5f
#define CHUNKS 49          // HW / 1024

typedef float v4f __attribute__((ext_vector_type(4)));  // native vec for nontemporal ld/st

// fast sigmoid: v_exp + v_rcp (error ~1e-6, budget is 3e-2)
__device__ __forceinline__ float fsig(float v) {
    float e = __expf(-v);
    return __builtin_amdgcn_rcpf(1.0f + e);
}
// tanh-form GELU == v*sigmoid(1.59577v + 0.071355v^3); max dev ~1e-3 << 3.3e-2 budget
__device__ __forceinline__ float fgelu(float v) {
    float t = v * (1.5957691216f + 0.0713548162f * v * v);
    return v * fsig(t);
}
__device__ __forceinline__ float edgew(int w) {
    return 1.0f + (float)((w == 1) | (w == 2) | (w == WW-3) | (w == WW-2));
}

// ---------------- Pass 1: block = (n, 1024-float spatial chunk). Each WAVE owns
// a 16-channel group over the whole chunk (4 float4/lane -> 4 independent loads
// in flight per iteration; const-trip-16 loop unrolls for MLP). 64-lane shfl
// reduce per channel, lane 0 writes partials. Register gate carry.
__global__ __launch_bounds__(256) void k_pool3(const float* __restrict__ x,
                                               float* __restrict__ partG,
                                               float* __restrict__ partX) {
    int b = blockIdx.x;
    int n = b / CHUNKS;
    int chunk = b - n * CHUNKS;
    int wave = threadIdx.x >> 6;
    int lane = threadIdx.x & 63;

    int p0 = chunk * 1024 + lane * 4;       // float4-aligned; WW%4==0 so row-safe
    float4 wgt[4];
    #pragma unroll
    for (int m = 0; m < 4; ++m) {
        int pm = p0 + m * 256;
        int h  = pm / WW;
        int w0 = pm - h * WW;
        float wh = 1.0f + (float)((h == 1) | (h == 2) | (h == HH-3) | (h == HH-2));
        wgt[m].x = wh * edgew(w0);
        wgt[m].y = wh * edgew(w0 + 1);
        wgt[m].z = wh * edgew(w0 + 2);
        wgt[m].w = wh * edgew(w0 + 3);
    }

    const float* xn = x + (size_t)n * CB * HW;
    int c0 = wave * 16;
    int cg = (c0 + CB - 1) & (CB - 1);      // gate channel for c0 (roll +1)
    float4 prev[4];
    #pragma unroll
    for (int m = 0; m < 4; ++m)
        prev[m] = *(const float4*)(xn + (size_t)cg * HW + p0 + m * 256);

    for (int k = 0; k < 16; ++k) {
        int c = c0 + k;
        float4 cur[4];
        #pragma unroll
        for (int m = 0; m < 4; ++m)
            cur[m] = *(const float4*)(xn + (size_t)c * HW + p0 + m * 256);
        float sG = 0.f, sX = 0.f;
        #pragma unroll
        for (int m = 0; m < 4; ++m) {
            sG += wgt[m].x * cur[m].x * fsig(prev[m].x);
            sG += wgt[m].y * cur[m].y * fsig(prev[m].y);
            sG += wgt[m].z * cur[m].z * fsig(prev[m].z);
            sG += wgt[m].w * cur[m].w * fsig(prev[m].w);
            sX += wgt[m].x * cur[m].x + wgt[m].y * cur[m].y
                + wgt[m].z * cur[m].z + wgt[m].w * cur[m].w;
            prev[m] = cur[m];
        }
        #pragma unroll
        for (int off = 32; off >= 1; off >>= 1) {
            sG += __shfl_xor(sG, off);
            sX += __shfl_xor(sX, off);
        }
        if (lane == 0) {
            size_t idx = ((size_t)n * CB + c) * CHUNKS + chunk;
            partG[idx] = sG;
            partX[idx] = sX;
        }
    }
}

// ---------------- Merged stats: fold 49 chunk-partials per (n,c), then BN
// (batch mean/biased var across n) + sigmoid -> scale; also writes cmean.
__global__ __launch_bounds__(256) void k_stats(const float* __restrict__ partG,
                                               const float* __restrict__ partX,
                                               const float* __restrict__ bnw,
                                               const float* __restrict__ bnb,
                                               float* __restrict__ cmean,
                                               float* __restrict__ scale) {
    int c = blockIdx.x;
    int t = threadIdx.x;
    int n = t >> 3, j0 = t & 7;
    float g = 0.f, xx = 0.f;
    for (int j = j0; j < CHUNKS; j += 8) {
        size_t idx = ((size_t)n * CB + c) * CHUNKS + j;
        g  += partG[idx];
        xx += partX[idx];
    }
    #pragma unroll
    for (int off = 4; off >= 1; off >>= 1) {
        g  += __shfl_xor(g, off);
        xx += __shfl_xor(xx, off);
    }
    __shared__ float lG[NB];
    if (j0 == 0) {
        lG[n] = g;
        cmean[n * CB + c] = xx * (1.0f / (float)HWP);
    }
    __syncthreads();
    if (t < NB) {
        float p = lG[t] * (1.0f / (float)HWP);     // pooled[t][c]
        float s = p;
        #pragma unroll
        for (int off = 16; off >= 1; off >>= 1) s += __shfl_xor(s, off);
        float mu = s * (1.0f / 32.0f);
        float d = p - mu;
        float q = d * d;
        #pragma unroll
        for (int off = 16; off >= 1; off >>= 1) q += __shfl_xor(q, off);
        float var = q * (1.0f / 32.0f);
        float normed = d * rsqrtf(var + EPSV) * bnw[c] + bnb[c];
        scale[t * CB + c] = 1.0f / (1.0f + expf(-normed));
    }
}

// ---------------- Output pass: XCD-swizzled block per (n, padded row hp);
// wave w handles channels [16w,16w+16) (const-trip-16 loop, forced unroll for
// load MLP). Lane l<56 loads aligned float4 rw=4l..4l+3 (nontemporal), computes
// o0..o3; shfl-up realigns so lanes 0..56 emit one ALIGNED nontemporal float4
// store covering the padded row (edge reflection folded into lanes 0/56).
__global__ __launch_bounds__(256) void k_out(const float* __restrict__ x,
                                             const float* __restrict__ scale,
                                             const float* __restrict__ cmean,
                                             const float* __restrict__ post_scale,
                                             float* __restrict__ out) {
    // XCD swizzle: 7296 blocks = 8 XCDs x 912 contiguous (n,hp) rows (4 images each).
    int o = blockIdx.x;
    int w = (o & 7) * (NB * HP / 8) + (o >> 3);
    int n  = w / HP;
    int hp = w - n * HP;
    int rh = hp - PADP; rh = rh < 0 ? -rh : (rh >= HH ? 2*HH - 2 - rh : rh);
    int wave = threadIdx.x >> 6;
    int lane = threadIdx.x & 63;
    bool act = lane < 56;
    float ps = post_scale[0];

    const float* xrow = x + (size_t)n * CB * HW + (size_t)rh * WW;
    const float* sc_row = scale + n * CB;
    const float* cm_row = cmean + n * CB;

    int c0 = wave * 16;
    int cg = (c0 + CB - 1) & (CB - 1);
    v4f prev = {0.f, 0.f, 0.f, 0.f};
    if (act) prev = __builtin_nontemporal_load((const v4f*)(xrow + (size_t)cg * HW + 4 * lane));

    #pragma unroll
    for (int k = 0; k < 16; ++k) {
        int c = c0 + k;
        v4f cur = {0.f, 0.f, 0.f, 0.f};
        if (act) cur = __builtin_nontemporal_load((const v4f*)(xrow + (size_t)c * HW + 4 * lane));
        float scp = sc_row[c] * ps;         // wave-uniform
        float cmp = cm_row[c] * ps;
        float o0 = fgelu(fmaf(cur.x * fsig(prev.x), scp, cmp));
        float o1 = fgelu(fmaf(cur.y * fsig(prev.y), scp, cmp));
        float o2 = fgelu(fmaf(cur.z * fsig(prev.z), scp, cmp));
        float o3 = fgelu(fmaf(cur.w * fsig(prev.w), scp, cmp));
        // shift left-neighbor's (o1,o2,o3) in: lane l store covers wp=4l..4l+3
        float o1s = __shfl(o1, lane - 1);
        float o2s = __shfl(o2, lane - 1);
        float o3s = __shfl(o3, lane - 1);
        v4f st = { o2s, o3s, o0, o1 };          // interior: rw 4l-2..4l+1
        if (lane == 0)  st = (v4f){ o2, o1, o0, o1 };        // wp0<-rw2, wp1<-rw1, wp2<-rw0, wp3<-rw1
        if (lane == 56) st = (v4f){ o2s, o3s, o2s, o1s };    // wp224..227 <- rw222,223,222,221
        if (lane < 57) {
            float* orow = out + ((size_t)n * CB + c) * HWP + (size_t)hp * WP;
            __builtin_nontemporal_store(st, (v4f*)(orow + 4 * lane));
        }
        prev = cur;
    }
}

extern "C" void kernel_launch(void* const* d_in, const int* in_sizes, int n_in,
                              void* d_out, int out_size, void* d_ws, size_t ws_size,
                              hipStream_t stream) {
    const float* x   = (const float*)d_in[0];
    const float* bnw = (const float*)d_in[1];
    const float* bnb = (const float*)d_in[2];
    const float* ps  = (const float*)d_in[3];
    float* out = (float*)d_out;

    size_t npart = (size_t)NB * CB * CHUNKS;
    float* partG  = (float*)d_ws;
    float* partX  = partG + npart;
    float* cmean  = partX + npart;
    float* scale  = cmean + NB * CB;

    k_pool3<<<NB * CHUNKS, 256, 0, stream>>>(x, partG, partX);
    k_stats<<<CB, 256, 0, stream>>>(partG, partX, bnw, bnb, cmean, scale);
    k_out<<<NB * HP, 256, 0, stream>>>(x, scale, cmean, ps, out);
}

// Round 9
// 241.979 us; speedup vs baseline: 1.1033x; 1.0449x over previous
//
#include <hip/hip_runtime.h>
#include <math.h>

#define NB 32
#define CB 64
#define HH 224
#define WW 224
#define PADP 2
#define HP (HH + 2*PADP)   // 228
#define WP (WW + 2*PADP)   // 228
#define HW (HH*WW)         // 50176
#define HWP (HP*WP)        // 51984
#define EPSV 1e-5f
#define CHUNKS 49          // HW / 1024

typedef float   v4f __attribute__((ext_vector_type(4)));
typedef _Float16 h4 __attribute__((ext_vector_type(4)));

// fast sigmoid: v_exp + v_rcp (error ~1e-6, budget is 3e-2)
__device__ __forceinline__ float fsig(float v) {
    float e = __expf(-v);
    return __builtin_amdgcn_rcpf(1.0f + e);
}
// tanh-form GELU == v*sigmoid(1.59577v + 0.071355v^3); max dev ~1e-3 << 3.3e-2 budget
__device__ __forceinline__ float fgelu(float v) {
    float t = v * (1.5957691216f + 0.0713548162f * v * v);
    return v * fsig(t);
}
__device__ __forceinline__ float edgew(int w) {
    return 1.0f + (float)((w == 1) | (w == 2) | (w == WW-3) | (w == WW-2));
}

// ---------------- Pass 1 (ws-large path): same structure as k_pool3 (16-channel
// waves, 4 float4/lane, unrolled for MLP) + stores gated=x*sig(roll) as fp16
// NCHW into ws (205 MB, fits L3; x loads are nontemporal so they don't evict it).
__global__ __launch_bounds__(256) void k_pool5(const float* __restrict__ x,
                                               _Float16* __restrict__ gat,
                                               float* __restrict__ partG,
                                               float* __restrict__ partX) {
    int b = blockIdx.x;
    int n = b / CHUNKS;
    int chunk = b - n * CHUNKS;
    int wave = threadIdx.x >> 6;
    int lane = threadIdx.x & 63;

    int p0 = chunk * 1024 + lane * 4;       // float4-aligned; WW%4==0 so row-safe
    float4 wgt[4];
    #pragma unroll
    for (int m = 0; m < 4; ++m) {
        int pm = p0 + m * 256;
        int h  = pm / WW;
        int w0 = pm - h * WW;
        float wh = 1.0f + (float)((h == 1) | (h == 2) | (h == HH-3) | (h == HH-2));
        wgt[m].x = wh * edgew(w0);
        wgt[m].y = wh * edgew(w0 + 1);
        wgt[m].z = wh * edgew(w0 + 2);
        wgt[m].w = wh * edgew(w0 + 3);
    }

    const float* xn = x + (size_t)n * CB * HW;
    _Float16* gn = gat + (size_t)n * CB * HW;
    int c0 = wave * 16;
    int cg = (c0 + CB - 1) & (CB - 1);      // gate channel for c0 (roll +1)
    v4f prev[4];
    #pragma unroll
    for (int m = 0; m < 4; ++m)
        prev[m] = __builtin_nontemporal_load((const v4f*)(xn + (size_t)cg * HW + p0 + m * 256));

    for (int k = 0; k < 16; ++k) {
        int c = c0 + k;
        v4f cur[4];
        #pragma unroll
        for (int m = 0; m < 4; ++m)
            cur[m] = __builtin_nontemporal_load((const v4f*)(xn + (size_t)c * HW + p0 + m * 256));
        float sG = 0.f, sX = 0.f;
        #pragma unroll
        for (int m = 0; m < 4; ++m) {
            float g0 = cur[m].x * fsig(prev[m].x);
            float g1 = cur[m].y * fsig(prev[m].y);
            float g2 = cur[m].z * fsig(prev[m].z);
            float g3 = cur[m].w * fsig(prev[m].w);
            sG += wgt[m].x * g0 + wgt[m].y * g1 + wgt[m].z * g2 + wgt[m].w * g3;
            sX += wgt[m].x * cur[m].x + wgt[m].y * cur[m].y
                + wgt[m].z * cur[m].z + wgt[m].w * cur[m].w;
            *(h4*)(gn + (size_t)c * HW + p0 + m * 256) =
                (h4){(_Float16)g0, (_Float16)g1, (_Float16)g2, (_Float16)g3};
            prev[m] = cur[m];
        }
        #pragma unroll
        for (int off = 32; off >= 1; off >>= 1) {
            sG += __shfl_xor(sG, off);
            sX += __shfl_xor(sX, off);
        }
        if (lane == 0) {
            size_t idx = ((size_t)n * CB + c) * CHUNKS + chunk;
            partG[idx] = sG;
            partX[idx] = sX;
        }
    }
}

// ---------------- Pass 1 (fallback, no gated staging) — round-8 k_pool3.
__global__ __launch_bounds__(256) void k_pool3(const float* __restrict__ x,
                                               float* __restrict__ partG,
                                               float* __restrict__ partX) {
    int b = blockIdx.x;
    int n = b / CHUNKS;
    int chunk = b - n * CHUNKS;
    int wave = threadIdx.x >> 6;
    int lane = threadIdx.x & 63;

    int p0 = chunk * 1024 + lane * 4;
    float4 wgt[4];
    #pragma unroll
    for (int m = 0; m < 4; ++m) {
        int pm = p0 + m * 256;
        int h  = pm / WW;
        int w0 = pm - h * WW;
        float wh = 1.0f + (float)((h == 1) | (h == 2) | (h == HH-3) | (h == HH-2));
        wgt[m].x = wh * edgew(w0);
        wgt[m].y = wh * edgew(w0 + 1);
        wgt[m].z = wh * edgew(w0 + 2);
        wgt[m].w = wh * edgew(w0 + 3);
    }
    const float* xn = x + (size_t)n * CB * HW;
    int c0 = wave * 16;
    int cg = (c0 + CB - 1) & (CB - 1);
    float4 prev[4];
    #pragma unroll
    for (int m = 0; m < 4; ++m)
        prev[m] = *(const float4*)(xn + (size_t)cg * HW + p0 + m * 256);

    for (int k = 0; k < 16; ++k) {
        int c = c0 + k;
        float4 cur[4];
        #pragma unroll
        for (int m = 0; m < 4; ++m)
            cur[m] = *(const float4*)(xn + (size_t)c * HW + p0 + m * 256);
        float sG = 0.f, sX = 0.f;
        #pragma unroll
        for (int m = 0; m < 4; ++m) {
            sG += wgt[m].x * cur[m].x * fsig(prev[m].x);
            sG += wgt[m].y * cur[m].y * fsig(prev[m].y);
            sG += wgt[m].z * cur[m].z * fsig(prev[m].z);
            sG += wgt[m].w * cur[m].w * fsig(prev[m].w);
            sX += wgt[m].x * cur[m].x + wgt[m].y * cur[m].y
                + wgt[m].z * cur[m].z + wgt[m].w * cur[m].w;
            prev[m] = cur[m];
        }
        #pragma unroll
        for (int off = 32; off >= 1; off >>= 1) {
            sG += __shfl_xor(sG, off);
            sX += __shfl_xor(sX, off);
        }
        if (lane == 0) {
            size_t idx = ((size_t)n * CB + c) * CHUNKS + chunk;
            partG[idx] = sG;
            partX[idx] = sX;
        }
    }
}

// ---------------- Merged stats: fold 49 chunk-partials per (n,c), then BN
// (batch mean/biased var across n) + sigmoid -> scale; also writes cmean.
__global__ __launch_bounds__(256) void k_stats(const float* __restrict__ partG,
                                               const float* __restrict__ partX,
                                               const float* __restrict__ bnw,
                                               const float* __restrict__ bnb,
                                               float* __restrict__ cmean,
                                               float* __restrict__ scale) {
    int c = blockIdx.x;
    int t = threadIdx.x;
    int n = t >> 3, j0 = t & 7;
    float g = 0.f, xx = 0.f;
    for (int j = j0; j < CHUNKS; j += 8) {
        size_t idx = ((size_t)n * CB + c) * CHUNKS + j;
        g  += partG[idx];
        xx += partX[idx];
    }
    #pragma unroll
    for (int off = 4; off >= 1; off >>= 1) {
        g  += __shfl_xor(g, off);
        xx += __shfl_xor(xx, off);
    }
    __shared__ float lG[NB];
    if (j0 == 0) {
        lG[n] = g;
        cmean[n * CB + c] = xx * (1.0f / (float)HWP);
    }
    __syncthreads();
    if (t < NB) {
        float p = lG[t] * (1.0f / (float)HWP);
        float s = p;
        #pragma unroll
        for (int off = 16; off >= 1; off >>= 1) s += __shfl_xor(s, off);
        float mu = s * (1.0f / 32.0f);
        float d = p - mu;
        float q = d * d;
        #pragma unroll
        for (int off = 16; off >= 1; off >>= 1) q += __shfl_xor(q, off);
        float var = q * (1.0f / 32.0f);
        float normed = d * rsqrtf(var + EPSV) * bnw[c] + bnb[c];
        scale[t * CB + c] = 1.0f / (1.0f + expf(-normed));
    }
}

// ---------------- Pass 2 (ws-large path): reads fp16 gated (L3-resident) only.
// XCD-swizzled block per (n,hp); wave w -> channels [16w,16w+16) unrolled.
// Lane l<56 loads 8B (4 fp16), computes o0..o3, shfl edge trick, nt v4f store.
__global__ __launch_bounds__(256) void k_outg(const _Float16* __restrict__ gat,
                                              const float* __restrict__ scale,
                                              const float* __restrict__ cmean,
                                              const float* __restrict__ post_scale,
                                              float* __restrict__ out) {
    int o = blockIdx.x;
    int w = (o & 7) * (NB * HP / 8) + (o >> 3);
    int n  = w / HP;
    int hp = w - n * HP;
    int rh = hp - PADP; rh = rh < 0 ? -rh : (rh >= HH ? 2*HH - 2 - rh : rh);
    int wave = threadIdx.x >> 6;
    int lane = threadIdx.x & 63;
    bool act = lane < 56;
    float ps = post_scale[0];

    const _Float16* grow = gat + (size_t)n * CB * HW + (size_t)rh * WW;
    const float* sc_row = scale + n * CB;
    const float* cm_row = cmean + n * CB;
    int c0 = wave * 16;

    #pragma unroll
    for (int k = 0; k < 16; ++k) {
        int c = c0 + k;
        h4 g = (h4){(_Float16)0, (_Float16)0, (_Float16)0, (_Float16)0};
        if (act) g = *(const h4*)(grow + (size_t)c * HW + 4 * lane);
        float scp = sc_row[c] * ps;         // wave-uniform
        float cmp = cm_row[c] * ps;
        float o0 = fgelu(fmaf((float)g.x, scp, cmp));
        float o1 = fgelu(fmaf((float)g.y, scp, cmp));
        float o2 = fgelu(fmaf((float)g.z, scp, cmp));
        float o3 = fgelu(fmaf((float)g.w, scp, cmp));
        float o1s = __shfl(o1, lane - 1);
        float o2s = __shfl(o2, lane - 1);
        float o3s = __shfl(o3, lane - 1);
        v4f st = { o2s, o3s, o0, o1 };          // interior: rw 4l-2..4l+1
        if (lane == 0)  st = (v4f){ o2, o1, o0, o1 };
        if (lane == 56) st = (v4f){ o2s, o3s, o2s, o1s };
        if (lane < 57) {
            float* orow = out + ((size_t)n * CB + c) * HWP + (size_t)hp * WP;
            __builtin_nontemporal_store(st, (v4f*)(orow + 4 * lane));
        }
    }
}

// ---------------- Pass 2 (fallback) — round-8 k_out (re-reads x).
__global__ __launch_bounds__(256) void k_out(const float* __restrict__ x,
                                             const float* __restrict__ scale,
                                             const float* __restrict__ cmean,
                                             const float* __restrict__ post_scale,
                                             float* __restrict__ out) {
    int o = blockIdx.x;
    int w = (o & 7) * (NB * HP / 8) + (o >> 3);
    int n  = w / HP;
    int hp = w - n * HP;
    int rh = hp - PADP; rh = rh < 0 ? -rh : (rh >= HH ? 2*HH - 2 - rh : rh);
    int wave = threadIdx.x >> 6;
    int lane = threadIdx.x & 63;
    bool act = lane < 56;
    float ps = post_scale[0];

    const float* xrow = x + (size_t)n * CB * HW + (size_t)rh * WW;
    const float* sc_row = scale + n * CB;
    const float* cm_row = cmean + n * CB;
    int c0 = wave * 16;
    int cg = (c0 + CB - 1) & (CB - 1);
    v4f prev = {0.f, 0.f, 0.f, 0.f};
    if (act) prev = __builtin_nontemporal_load((const v4f*)(xrow + (size_t)cg * HW + 4 * lane));

    #pragma unroll
    for (int k = 0; k < 16; ++k) {
        int c = c0 + k;
        v4f cur = {0.f, 0.f, 0.f, 0.f};
        if (act) cur = __builtin_nontemporal_load((const v4f*)(xrow + (size_t)c * HW + 4 * lane));
        float scp = sc_row[c] * ps;
        float cmp = cm_row[c] * ps;
        float o0 = fgelu(fmaf(cur.x * fsig(prev.x), scp, cmp));
        float o1 = fgelu(fmaf(cur.y * fsig(prev.y), scp, cmp));
        float o2 = fgelu(fmaf(cur.z * fsig(prev.z), scp, cmp));
        float o3 = fgelu(fmaf(cur.w * fsig(prev.w), scp, cmp));
        float o1s = __shfl(o1, lane - 1);
        float o2s = __shfl(o2, lane - 1);
        float o3s = __shfl(o3, lane - 1);
        v4f st = { o2s, o3s, o0, o1 };
        if (lane == 0)  st = (v4f){ o2, o1, o0, o1 };
        if (lane == 56) st = (v4f){ o2s, o3s, o2s, o1s };
        if (lane < 57) {
            float* orow = out + ((size_t)n * CB + c) * HWP + (size_t)hp * WP;
            __builtin_nontemporal_store(st, (v4f*)(orow + 4 * lane));
        }
        prev = cur;
    }
}

extern "C" void kernel_launch(void* const* d_in, const int* in_sizes, int n_in,
                              void* d_out, int out_size, void* d_ws, size_t ws_size,
                              hipStream_t stream) {
    const float* x   = (const float*)d_in[0];
    const float* bnw = (const float*)d_in[1];
    const float* bnb = (const float*)d_in[2];
    const float* ps  = (const float*)d_in[3];
    float* out = (float*)d_out;

    size_t npart = (size_t)NB * CB * CHUNKS;
    size_t ngat  = (size_t)NB * CB * HW;            // fp16 elements
    size_t need  = ngat * 2 + (2 * npart + 2 * (size_t)NB * CB) * 4;

    if (ws_size >= need) {
        _Float16* gat  = (_Float16*)d_ws;
        float* partG  = (float*)((char*)d_ws + ngat * 2);
        float* partX  = partG + npart;
        float* cmean  = partX + npart;
        float* scale  = cmean + NB * CB;
        k_pool5<<<NB * CHUNKS, 256, 0, stream>>>(x, gat, partG, partX);
        k_stats<<<CB, 256, 0, stream>>>(partG, partX, bnw, bnb, cmean, scale);
        k_outg<<<NB * HP, 256, 0, stream>>>(gat, scale, cmean, ps, out);
    } else {
        float* partG  = (float*)d_ws;
        float* partX  = partG + npart;
        float* cmean  = partX + npart;
        float* scale  = cmean + NB * CB;
        k_pool3<<<NB * CHUNKS, 256, 0, stream>>>(x, partG, partX);
        k_stats<<<CB, 256, 0, stream>>>(partG, partX, bnw, bnb, cmean, scale);
        k_out<<<NB * HP, 256, 0, stream>>>(x, scale, cmean, ps, out);
    }
}